// Round 3
// baseline (186.699 us; speedup 1.0000x reference)
//
#include <hip/hip_runtime.h>

// HierarchicalEmbedding: e = s_new*lam + t_new*(1-lam)
//   s_new[i] = s[i] (i<nwp) else e_prime[cp[i]];  e_prime[j] = s[j]*lam[j] + t[j]*(1-lam[j])
//   t_new[i] = mean_{k<5} t[children_idx[5i+k]] (i<nwc) else t[i]
//
// Branch-free formulation (maximizes load clustering / bytes-in-flight):
//   i<nwp   -> j=i, lam_j=1.0  => s_new = s[i]
//   i>=nwc  -> all 5 children = i => mean = t[i] (up to 1 ulp; threshold 4.9e-3)
// 32 lanes/row, float4/lane; 2 rows per lane-group unrolled, loads issued
// for both rows before any consumer waits.

constexpr int E = 128;

__global__ void __launch_bounds__(256)
he_kernel(const float* __restrict__ s,
          const float* __restrict__ t,
          const float* __restrict__ lambda_,
          const int* __restrict__ cp,
          const int* __restrict__ children_idx,
          const int* __restrict__ nwc_p,
          const int* __restrict__ nwp_p,
          float* __restrict__ out,
          int n_rows)
{
    const int gid  = blockIdx.x * blockDim.x + threadIdx.x;
    const int grp  = gid >> 5;               // 32-lane group
    const int col  = (gid & 31) << 2;        // float4 column offset
    const int row0 = grp * 2;
    if (row0 >= n_rows) return;
    const int row1_raw = row0 + 1;
    const int row1 = row1_raw < n_rows ? row1_raw : n_rows - 1;

    const int nwc = *nwc_p;
    const int nwp = *nwp_p;

    // ---------- level-0 loads (all independent) ----------
    const float lam0 = lambda_[row0];
    const float lam1 = lambda_[row1];
    const int jr0 = cp[row0];
    const int jr1 = cp[row1];
    const bool p0 = row0 < nwp,  p1 = row1 < nwp;
    const bool c0 = row0 < nwc,  c1 = row1 < nwc;
    const int j0 = p0 ? row0 : jr0;
    const int j1 = p1 ? row1 : jr1;

    const int b0 = row0 * 5, b1 = row1 * 5;
    int ca0 = children_idx[c0 ? b0 + 0 : 0];
    int ca1 = children_idx[c0 ? b0 + 1 : 0];
    int ca2 = children_idx[c0 ? b0 + 2 : 0];
    int ca3 = children_idx[c0 ? b0 + 3 : 0];
    int ca4 = children_idx[c0 ? b0 + 4 : 0];
    int cb0 = children_idx[c1 ? b1 + 0 : 0];
    int cb1 = children_idx[c1 ? b1 + 1 : 0];
    int cb2 = children_idx[c1 ? b1 + 2 : 0];
    int cb3 = children_idx[c1 ? b1 + 3 : 0];
    int cb4 = children_idx[c1 ? b1 + 4 : 0];
    ca0 = c0 ? ca0 : row0;  ca1 = c0 ? ca1 : row0;  ca2 = c0 ? ca2 : row0;
    ca3 = c0 ? ca3 : row0;  ca4 = c0 ? ca4 : row0;
    cb0 = c1 ? cb0 : row1;  cb1 = c1 ? cb1 : row1;  cb2 = c1 ? cb2 : row1;
    cb3 = c1 ? cb3 : row1;  cb4 = c1 ? cb4 : row1;

    // ---------- level-1 loads (dependent on indices; all independent of each other) ----------
    const float ljr0 = lambda_[j0];
    const float ljr1 = lambda_[j1];
    const float4 sj0 = *reinterpret_cast<const float4*>(s + (size_t)j0 * E + col);
    const float4 tj0 = *reinterpret_cast<const float4*>(t + (size_t)j0 * E + col);
    const float4 sj1 = *reinterpret_cast<const float4*>(s + (size_t)j1 * E + col);
    const float4 tj1 = *reinterpret_cast<const float4*>(t + (size_t)j1 * E + col);

    const float4 ta0 = *reinterpret_cast<const float4*>(t + (size_t)ca0 * E + col);
    const float4 ta1 = *reinterpret_cast<const float4*>(t + (size_t)ca1 * E + col);
    const float4 ta2 = *reinterpret_cast<const float4*>(t + (size_t)ca2 * E + col);
    const float4 ta3 = *reinterpret_cast<const float4*>(t + (size_t)ca3 * E + col);
    const float4 ta4 = *reinterpret_cast<const float4*>(t + (size_t)ca4 * E + col);
    const float4 tb0 = *reinterpret_cast<const float4*>(t + (size_t)cb0 * E + col);
    const float4 tb1 = *reinterpret_cast<const float4*>(t + (size_t)cb1 * E + col);
    const float4 tb2 = *reinterpret_cast<const float4*>(t + (size_t)cb2 * E + col);
    const float4 tb3 = *reinterpret_cast<const float4*>(t + (size_t)cb3 * E + col);
    const float4 tb4 = *reinterpret_cast<const float4*>(t + (size_t)cb4 * E + col);

    // ---------- compute row0 ----------
    const float lj0 = p0 ? 1.0f : ljr0;
    float4 sv0;
    sv0.x = sj0.x * lj0 + tj0.x * (1.0f - lj0);
    sv0.y = sj0.y * lj0 + tj0.y * (1.0f - lj0);
    sv0.z = sj0.z * lj0 + tj0.z * (1.0f - lj0);
    sv0.w = sj0.w * lj0 + tj0.w * (1.0f - lj0);
    float4 tv0;
    tv0.x = (ta0.x + ta1.x + ta2.x + ta3.x + ta4.x) * 0.2f;
    tv0.y = (ta0.y + ta1.y + ta2.y + ta3.y + ta4.y) * 0.2f;
    tv0.z = (ta0.z + ta1.z + ta2.z + ta3.z + ta4.z) * 0.2f;
    tv0.w = (ta0.w + ta1.w + ta2.w + ta3.w + ta4.w) * 0.2f;
    float4 ev0;
    ev0.x = sv0.x * lam0 + tv0.x * (1.0f - lam0);
    ev0.y = sv0.y * lam0 + tv0.y * (1.0f - lam0);
    ev0.z = sv0.z * lam0 + tv0.z * (1.0f - lam0);
    ev0.w = sv0.w * lam0 + tv0.w * (1.0f - lam0);
    *reinterpret_cast<float4*>(out + (size_t)row0 * E + col) = ev0;

    // ---------- compute row1 ----------
    const float lj1 = p1 ? 1.0f : ljr1;
    float4 sv1;
    sv1.x = sj1.x * lj1 + tj1.x * (1.0f - lj1);
    sv1.y = sj1.y * lj1 + tj1.y * (1.0f - lj1);
    sv1.z = sj1.z * lj1 + tj1.z * (1.0f - lj1);
    sv1.w = sj1.w * lj1 + tj1.w * (1.0f - lj1);
    float4 tv1;
    tv1.x = (tb0.x + tb1.x + tb2.x + tb3.x + tb4.x) * 0.2f;
    tv1.y = (tb0.y + tb1.y + tb2.y + tb3.y + tb4.y) * 0.2f;
    tv1.z = (tb0.z + tb1.z + tb2.z + tb3.z + tb4.z) * 0.2f;
    tv1.w = (tb0.w + tb1.w + tb2.w + tb3.w + tb4.w) * 0.2f;
    float4 ev1;
    ev1.x = sv1.x * lam1 + tv1.x * (1.0f - lam1);
    ev1.y = sv1.y * lam1 + tv1.y * (1.0f - lam1);
    ev1.z = sv1.z * lam1 + tv1.z * (1.0f - lam1);
    ev1.w = sv1.w * lam1 + tv1.w * (1.0f - lam1);
    if (row1_raw < n_rows)
        *reinterpret_cast<float4*>(out + (size_t)row1 * E + col) = ev1;
}

extern "C" void kernel_launch(void* const* d_in, const int* in_sizes, int n_in,
                              void* d_out, int out_size, void* d_ws, size_t ws_size,
                              hipStream_t stream)
{
    const float* s            = (const float*)d_in[0];
    const float* t            = (const float*)d_in[1];
    const float* lambda_      = (const float*)d_in[2];
    const int*   cp           = (const int*)d_in[3];
    const int*   children_idx = (const int*)d_in[4];
    // d_in[5] = seg_ids (implicit repeat(arange(nwc),5), unused)
    const int*   nwc_p        = (const int*)d_in[6];
    const int*   nwp_p        = (const int*)d_in[7];

    float* out = (float*)d_out;
    const int n_rows = in_sizes[0] / E;          // NODE_NUM+1

    const int threads = 256;                     // 8 groups/block, 2 rows/group = 16 rows/block
    const int n_groups = (n_rows + 1) / 2;
    const int blocks = (n_groups * 32 + threads - 1) / threads;

    he_kernel<<<blocks, threads, 0, stream>>>(s, t, lambda_, cp, children_idx,
                                              nwc_p, nwp_p, out, n_rows);
}